// Round 3
// baseline (1211.022 us; speedup 1.0000x reference)
//
#include <hip/hip_runtime.h>

#define IN_DIM 512
#define HID 64
#define OUT_DIM 5

// ---------------- bf16 helpers (RNE) ----------------

__device__ __forceinline__ unsigned short f2bf(float f) {
    unsigned u = __float_as_uint(f);
    u += 0x7FFF + ((u >> 16) & 1);
    return (unsigned short)(u >> 16);
}
__device__ __forceinline__ float bf2f(unsigned short b) {
    return __uint_as_float(((unsigned)b) << 16);
}

// edge record unpack: int2 loaded as 64-bit (low = src, high = weight bits)
__device__ __forceinline__ int ed_src(long long v) { return (int)(v & 0xffffffffLL); }
__device__ __forceinline__ float ed_w(long long v) { return __int_as_float((int)(v >> 32)); }

// ---------------- init: packed deg/count accumulator = 0 ----------------

__global__ void k_init(unsigned long long* __restrict__ packed, int n) {
    int i = blockIdx.x * blockDim.x + threadIdx.x;
    if (i < n) packed[i] = 0ULL;
}

// ---------------- hist: ONE packed 64-bit atomic per edge, 4 edges/thread ----------------
// packed[d]: bits [63:44] = incoming-edge count, [43:0] = sum(ew) in 12.32 fixed pt.
// atomic return gives this edge's rank within its dst bucket for free.
// 4 independent atomics in flight per thread: latency-vs-throughput probe for the
// fabric atomic path (VALUBusy was 1%, HBM 11% -> not VALU/BW bound).

__global__ void k_hist4(const int* __restrict__ dst, const float* __restrict__ ew,
                        unsigned long long* __restrict__ packed, int* __restrict__ rank, int nE) {
    int base = (blockIdx.x * blockDim.x + threadIdx.x) * 4;
    if (base + 3 < nE) {
        int4   d4 = *(const int4*)&dst[base];
        float4 w4 = *(const float4*)&ew[base];
        unsigned long long f0 = (unsigned long long)(w4.x * 4294967296.0);
        unsigned long long f1 = (unsigned long long)(w4.y * 4294967296.0);
        unsigned long long f2 = (unsigned long long)(w4.z * 4294967296.0);
        unsigned long long f3 = (unsigned long long)(w4.w * 4294967296.0);
        unsigned long long o0 = atomicAdd(&packed[d4.x], (1ULL << 44) | f0);
        unsigned long long o1 = atomicAdd(&packed[d4.y], (1ULL << 44) | f1);
        unsigned long long o2 = atomicAdd(&packed[d4.z], (1ULL << 44) | f2);
        unsigned long long o3 = atomicAdd(&packed[d4.w], (1ULL << 44) | f3);
        int4 r4;
        r4.x = (int)(o0 >> 44);
        r4.y = (int)(o1 >> 44);
        r4.z = (int)(o2 >> 44);
        r4.w = (int)(o3 >> 44);
        *(int4*)&rank[base] = r4;
    } else {
        for (int e = base; e < nE; ++e) {
            int d = dst[e];
            unsigned long long fx = (unsigned long long)(ew[e] * 4294967296.0);
            unsigned long long old = atomicAdd(&packed[d], (1ULL << 44) | fx);
            rank[e] = (int)(old >> 44);
        }
    }
}

// ---------------- unpack: dinv = rsqrt(1 + sum_ew), cnt for scan ----------------

__global__ void k_dinv(const unsigned long long* __restrict__ packed,
                       float* __restrict__ dinv, int* __restrict__ cnt, int n) {
    int i = blockIdx.x * blockDim.x + threadIdx.x;
    if (i < n) {
        unsigned long long p = packed[i];
        int c = (int)(p >> 44);
        double ewsum = (double)(p & ((1ULL << 44) - 1)) * (1.0 / 4294967296.0);
        float deg = 1.0f + (float)ewsum;  // self-loop weight 1 => deg >= 1 always
        dinv[i] = rsqrtf(deg);
        cnt[i] = c;
    }
}

// ---------------- exclusive scan of cnt -> rowptr (3-kernel hierarchical) ----------------

__global__ void k_scan1(const int* __restrict__ cnt, int* __restrict__ rowptr,
                        int* __restrict__ bsum, int n) {
    __shared__ int sdata[256];
    int t = threadIdx.x, b = blockIdx.x;
    int base = b * 1024 + t * 4;
    int v[4], s = 0;
#pragma unroll
    for (int k = 0; k < 4; ++k) { int i = base + k; v[k] = (i < n) ? cnt[i] : 0; s += v[k]; }
    sdata[t] = s;
    __syncthreads();
    int x = s;
    for (int off = 1; off < 256; off <<= 1) {
        int y = (t >= off) ? sdata[t - off] : 0;
        __syncthreads();
        x += y;
        sdata[t] = x;
        __syncthreads();
    }
    int run = x - s;
    if (t == 255) bsum[b] = x;
#pragma unroll
    for (int k = 0; k < 4; ++k) { int i = base + k; if (i < n) rowptr[i] = run; run += v[k]; }
}

__global__ void k_scan2(int* __restrict__ bsum, int nb) {
    __shared__ int sdata[256];
    int t = threadIdx.x;
    int s = (t < nb) ? bsum[t] : 0;
    sdata[t] = s;
    __syncthreads();
    int x = s;
    for (int off = 1; off < 256; off <<= 1) {
        int y = (t >= off) ? sdata[t - off] : 0;
        __syncthreads();
        x += y;
        sdata[t] = x;
        __syncthreads();
    }
    if (t < nb) bsum[t] = x - s;
}

__global__ void k_scan3(int* __restrict__ rowptr, const int* __restrict__ bsum, int n, int E) {
    int i = blockIdx.x * blockDim.x + threadIdx.x;
    if (i < n) rowptr[i] += bsum[i >> 10];
    else if (i == n) rowptr[n] = E;
}

// ---------------- reorder: NO atomics — pos = rowptr[dst] + rank ----------------

__global__ void k_reorder(const int* __restrict__ src, const int* __restrict__ dst,
                          const float* __restrict__ ew, const float* __restrict__ dinv,
                          const int* __restrict__ rowptr, const int* __restrict__ rank,
                          int2* __restrict__ edges, int nE) {
    int e = blockIdx.x * blockDim.x + threadIdx.x;
    if (e < nE) {
        int s = src[e];
        int d = dst[e];
        float w = dinv[s] * ew[e] * dinv[d];
        int pos = rowptr[d] + rank[e];
        edges[pos] = make_int2(s, __float_as_int(w));
    }
}

// ---------------- aggregate, feature-quarter sliced ----------------
// outq[q][n][f] = dinv[n]^2*h[n][q*16+f] + sum_e w_e * hbq[q][src_e][f]
// Gather table per quarter = N*16*2B = 3.2 MB < 4 MiB per-XCD L2 -> gathers L2-hit.
// grid(NB, 4): x-major dispatch means all XCDs process one quarter phase at a time.
// wave = one node; lane = (slot 4 parallel edges) x (16 features); cross-slot
// reduction via 2 shfl_xor. Edges/outputs use non-temporal hints to protect
// the L2-resident hbq slice from streaming pollution.

__launch_bounds__(256)
__global__ void k_aggregate_q(const float* __restrict__ h,            // [N][64] fp32
                              const unsigned short* __restrict__ hbq, // [4][N][16] bf16
                              const float* __restrict__ dinv,
                              const int2* __restrict__ edges, const int* __restrict__ rowptr,
                              float* __restrict__ outq,               // [4][N][16] fp32
                              int N) {
    const int q    = blockIdx.y;
    const int wave = threadIdx.x >> 6;
    const int n    = blockIdx.x * 4 + wave;
    if (n >= N) return;
    const int lane = threadIdx.x & 63;
    const int slot = lane >> 4;
    const int f    = lane & 15;

    const unsigned short* __restrict__ hq = hbq + (size_t)q * N * 16;
    const long long* __restrict__ edg = (const long long*)edges;

    float dn  = dinv[n];
    float acc = 0.f;
    if (slot == 0) acc = dn * dn * h[(size_t)n * 64 + q * 16 + f];

    const int beg = rowptr[n], end = rowptr[n + 1];
    int j = beg + slot;
    for (; j + 4 < end; j += 8) {
        long long p0 = __builtin_nontemporal_load(&edg[j]);
        long long p1 = __builtin_nontemporal_load(&edg[j + 4]);
        float h0 = bf2f(hq[(size_t)ed_src(p0) * 16 + f]);
        float h1 = bf2f(hq[(size_t)ed_src(p1) * 16 + f]);
        acc = fmaf(ed_w(p0), h0, acc);
        acc = fmaf(ed_w(p1), h1, acc);
    }
    if (j < end) {
        long long p = __builtin_nontemporal_load(&edg[j]);
        acc = fmaf(ed_w(p), bf2f(hq[(size_t)ed_src(p) * 16 + f]), acc);
    }

    acc += __shfl_xor(acc, 16, 64);
    acc += __shfl_xor(acc, 32, 64);

    if (slot == 0)
        __builtin_nontemporal_store(acc, &outq[((size_t)q * N + n) * 16 + f]);
}

// ---------------- tiled GEMM: out[M,64] = act(A) @ W[K,64]; bf16 copy quarter-major ----
// QMAJOR_A: A is stored [4][M][16] (quarter-major) instead of [M][K_].

template <int K_, bool RELU_BIAS, bool QMAJOR_A>
__launch_bounds__(256)
__global__ void k_gemm_n64(const float* __restrict__ A, const float* __restrict__ W,
                           const float* __restrict__ bias, float* __restrict__ out,
                           unsigned short* __restrict__ outb, int M) {
    constexpr int BK = 16;
    __shared__ float As[BK][68];
    __shared__ float Ws[BK][64];

    const int t  = threadIdx.x;
    const int tx = t & 15;
    const int ty = t >> 4;
    const int row0 = blockIdx.x * 64;

    const int lr = t >> 2;
    const int lk = (t & 3) * 4;

    float acc[4][4] = {};

    for (int k0 = 0; k0 < K_; k0 += BK) {
        float4 av = make_float4(0.f, 0.f, 0.f, 0.f);
        int ar = row0 + lr;
        if (ar < M) {
            const float* ap = QMAJOR_A
                ? &A[((size_t)(k0 >> 4) * M + ar) * 16 + lk]
                : &A[(long long)ar * K_ + k0 + lk];
            av = *(const float4*)ap;
            if (RELU_BIAS) {
                const float4 bv = *(const float4*)&bias[k0 + lk];
                av.x = fmaxf(av.x + bv.x, 0.f);
                av.y = fmaxf(av.y + bv.y, 0.f);
                av.z = fmaxf(av.z + bv.z, 0.f);
                av.w = fmaxf(av.w + bv.w, 0.f);
            }
        }
        As[lk + 0][lr] = av.x;
        As[lk + 1][lr] = av.y;
        As[lk + 2][lr] = av.z;
        As[lk + 3][lr] = av.w;

        *(float4*)&Ws[t >> 4][(t & 15) * 4] =
            *(const float4*)&W[(long long)(k0 + (t >> 4)) * 64 + (t & 15) * 4];

        __syncthreads();

#pragma unroll
        for (int kk = 0; kk < BK; ++kk) {
            float4 a4 = *(const float4*)&As[kk][ty * 4];
            float4 b4 = *(const float4*)&Ws[kk][tx * 4];
            float a[4] = {a4.x, a4.y, a4.z, a4.w};
            float b[4] = {b4.x, b4.y, b4.z, b4.w};
#pragma unroll
            for (int i = 0; i < 4; ++i)
#pragma unroll
                for (int j = 0; j < 4; ++j)
                    acc[i][j] = fmaf(a[i], b[j], acc[i][j]);
        }
        __syncthreads();
    }

    const int colq = (tx * 4) >> 4;      // quarter of this thread's 4 columns
    const int colf = (tx * 4) & 15;      // offset within quarter
#pragma unroll
    for (int i = 0; i < 4; ++i) {
        int r = row0 + ty * 4 + i;
        if (r < M) {
            *(float4*)&out[(long long)r * 64 + tx * 4] =
                make_float4(acc[i][0], acc[i][1], acc[i][2], acc[i][3]);
            ushort4 hv;
            hv.x = f2bf(acc[i][0]);
            hv.y = f2bf(acc[i][1]);
            hv.z = f2bf(acc[i][2]);
            hv.w = f2bf(acc[i][3]);
            *(ushort4*)&outb[((size_t)colq * M + r) * 16 + colf] = hv;
        }
    }
}

// ---------------- final: out[n,:5] = relu(agg[n,:]+b2) @ Wfc + bfc (agg quarter-major) ----

__launch_bounds__(256)
__global__ void k_final(const float* __restrict__ agg, const float* __restrict__ b2,
                        const float* __restrict__ Wfc, const float* __restrict__ bfc,
                        float* __restrict__ out, int N) {
    __shared__ float Wsf[HID * OUT_DIM];
    __shared__ float bs[HID];
    int t = threadIdx.x;
    for (int i = t; i < HID * OUT_DIM; i += 256) Wsf[i] = Wfc[i];
    if (t < HID) bs[t] = b2[t];
    __syncthreads();

    int n = blockIdx.x * blockDim.x + t;
    if (n >= N) return;

    float acc[OUT_DIM];
#pragma unroll
    for (int o = 0; o < OUT_DIM; ++o) acc[o] = bfc[o];

#pragma unroll
    for (int q = 0; q < 4; ++q) {
        const float4* ag = (const float4*)&agg[((size_t)q * N + n) * 16];
#pragma unroll
        for (int k4 = 0; k4 < 4; ++k4) {
            float4 v4 = ag[k4];
            float v[4] = {v4.x, v4.y, v4.z, v4.w};
#pragma unroll
            for (int j = 0; j < 4; ++j) {
                int k = q * 16 + k4 * 4 + j;
                float f = fmaxf(v[j] + bs[k], 0.f);
#pragma unroll
                for (int o = 0; o < OUT_DIM; ++o)
                    acc[o] = fmaf(f, Wsf[k * OUT_DIM + o], acc[o]);
            }
        }
    }
#pragma unroll
    for (int o = 0; o < OUT_DIM; ++o) out[(long long)n * OUT_DIM + o] = acc[o];
}

// ---------------- host launch ----------------

static inline size_t align_up(size_t x, size_t a) { return (x + a - 1) & ~(a - 1); }

extern "C" void kernel_launch(void* const* d_in, const int* in_sizes, int n_in,
                              void* d_out, int out_size, void* d_ws, size_t ws_size,
                              hipStream_t stream) {
    const float* x   = (const float*)d_in[0];
    const int*   ei  = (const int*)d_in[1];   // [2][E] int32
    const float* ew  = (const float*)d_in[2];
    const float* W1  = (const float*)d_in[3];
    const float* b1  = (const float*)d_in[4];
    const float* W2  = (const float*)d_in[5];
    const float* b2  = (const float*)d_in[6];
    const float* Wfc = (const float*)d_in[7];
    const float* bfc = (const float*)d_in[8];
    float* out = (float*)d_out;

    const int E = in_sizes[2];              // 3200000
    const int N = in_sizes[0] / IN_DIM;     // 100000
    const int* src = ei;
    const int* dst = ei + E;

    // workspace carve (hbq aliases rank: rank is dead after k_reorder,
    // GEMM1 writes hbq strictly after — same stream, sequential)
    char* p = (char*)d_ws;
    unsigned long long* packed = (unsigned long long*)p; p += align_up((size_t)N * 8, 256);
    float* dinv   = (float*)p;  p += align_up((size_t)N * 4, 256);
    int*   cnt    = (int*)p;    p += align_up((size_t)N * 4, 256);
    int*   rowptr = (int*)p;    p += align_up((size_t)(N + 1) * 4, 256);
    int*   bsum   = (int*)p;    p += align_up((size_t)256 * 4, 256);
    int*   rank   = (int*)p;    p += align_up((size_t)E * 4, 256);   // 12.8 MB
    unsigned short* hbq = (unsigned short*)rank;                      // 4*N*16*2 = 12.8 MB
    int2*  edges  = (int2*)p;   p += align_up((size_t)E * 8, 256);
    float* bufA   = (float*)p;  p += align_up((size_t)N * HID * 4, 256);
    float* bufB   = (float*)p;  p += align_up((size_t)N * HID * 4, 256);
    (void)ws_size; (void)n_in; (void)out_size;

    const int BS = 256;
    dim3 blk(BS);
    int gN  = (N + BS - 1) / BS;
    int gN1 = (N + 1 + BS - 1) / BS;
    int gE  = (E + BS - 1) / BS;
    int gE4 = (E + BS * 4 - 1) / (BS * 4);
    int gM  = (N + 63) / 64;
    int nb  = (N + 1023) / 1024;
    dim3 gAgg((N + 3) / 4, 4);   // x = node groups, y = quarter (x-major dispatch)

    // CSR build: 1 scattered atomic per edge total
    k_init<<<gN, blk, 0, stream>>>(packed, N);
    k_hist4<<<gE4, blk, 0, stream>>>(dst, ew, packed, rank, E);
    k_dinv<<<gN, blk, 0, stream>>>(packed, dinv, cnt, N);
    k_scan1<<<nb, blk, 0, stream>>>(cnt, rowptr, bsum, N);
    k_scan2<<<1, blk, 0, stream>>>(bsum, nb);
    k_scan3<<<gN1, blk, 0, stream>>>(rowptr, bsum, N, E);
    k_reorder<<<gE, blk, 0, stream>>>(src, dst, ew, dinv, rowptr, rank, edges, E);

    // layer 1 (hbq overwrites rank — rank dead from here on)
    k_gemm_n64<IN_DIM, false, false><<<gM, blk, 0, stream>>>(x, W1, nullptr, bufA, hbq, N);
    k_aggregate_q<<<gAgg, blk, 0, stream>>>(bufA, hbq, dinv, edges, rowptr, bufB, N);

    // layer 2 (A quarter-major from aggregate)
    k_gemm_n64<HID, true, true><<<gM, blk, 0, stream>>>(bufB, W2, b1, bufA, hbq, N);
    k_aggregate_q<<<gAgg, blk, 0, stream>>>(bufA, hbq, dinv, edges, rowptr, bufB, N);

    // final FC (agg quarter-major)
    k_final<<<gN, blk, 0, stream>>>(bufB, b2, Wfc, bfc, out, N);
}

// Round 4
// 822.405 us; speedup vs baseline: 1.4725x; 1.4725x over previous
//
#include <hip/hip_runtime.h>

#define IN_DIM 512
#define HID 64
#define OUT_DIM 5

// ---------------- bf16 helpers (RNE) ----------------

__device__ __forceinline__ unsigned short f2bf(float f) {
    unsigned u = __float_as_uint(f);
    u += 0x7FFF + ((u >> 16) & 1);
    return (unsigned short)(u >> 16);
}
__device__ __forceinline__ float bf2f(unsigned short b) {
    return __uint_as_float(((unsigned)b) << 16);
}

// ---------------- init: packed deg/count accumulator = 0 ----------------

__global__ void k_init(unsigned long long* __restrict__ packed, int n) {
    int i = blockIdx.x * blockDim.x + threadIdx.x;
    if (i < n) packed[i] = 0ULL;
}

// ---------------- hist: ONE packed 64-bit atomic per edge, 4 edges/thread ----------------
// packed[d]: bits [63:44] = incoming-edge count, [43:0] = sum(ew) in 12.32 fixed pt.
// atomic return gives this edge's rank within its dst bucket for free.
// 4 independent atomics in flight per thread (latency-vs-throughput probe).

__global__ void k_hist4(const int* __restrict__ dst, const float* __restrict__ ew,
                        unsigned long long* __restrict__ packed, int* __restrict__ rank, int nE) {
    int base = (blockIdx.x * blockDim.x + threadIdx.x) * 4;
    if (base + 3 < nE) {
        int4   d4 = *(const int4*)&dst[base];
        float4 w4 = *(const float4*)&ew[base];
        unsigned long long f0 = (unsigned long long)(w4.x * 4294967296.0);
        unsigned long long f1 = (unsigned long long)(w4.y * 4294967296.0);
        unsigned long long f2 = (unsigned long long)(w4.z * 4294967296.0);
        unsigned long long f3 = (unsigned long long)(w4.w * 4294967296.0);
        unsigned long long o0 = atomicAdd(&packed[d4.x], (1ULL << 44) | f0);
        unsigned long long o1 = atomicAdd(&packed[d4.y], (1ULL << 44) | f1);
        unsigned long long o2 = atomicAdd(&packed[d4.z], (1ULL << 44) | f2);
        unsigned long long o3 = atomicAdd(&packed[d4.w], (1ULL << 44) | f3);
        int4 r4;
        r4.x = (int)(o0 >> 44);
        r4.y = (int)(o1 >> 44);
        r4.z = (int)(o2 >> 44);
        r4.w = (int)(o3 >> 44);
        *(int4*)&rank[base] = r4;
    } else {
        for (int e = base; e < nE; ++e) {
            int d = dst[e];
            unsigned long long fx = (unsigned long long)(ew[e] * 4294967296.0);
            unsigned long long old = atomicAdd(&packed[d], (1ULL << 44) | fx);
            rank[e] = (int)(old >> 44);
        }
    }
}

// ---------------- unpack: dinv = rsqrt(1 + sum_ew), cnt for scan ----------------

__global__ void k_dinv(const unsigned long long* __restrict__ packed,
                       float* __restrict__ dinv, int* __restrict__ cnt, int n) {
    int i = blockIdx.x * blockDim.x + threadIdx.x;
    if (i < n) {
        unsigned long long p = packed[i];
        int c = (int)(p >> 44);
        double ewsum = (double)(p & ((1ULL << 44) - 1)) * (1.0 / 4294967296.0);
        float deg = 1.0f + (float)ewsum;  // self-loop weight 1 => deg >= 1 always
        dinv[i] = rsqrtf(deg);
        cnt[i] = c;
    }
}

// ---------------- exclusive scan of cnt -> rowptr (3-kernel hierarchical) ----------------

__global__ void k_scan1(const int* __restrict__ cnt, int* __restrict__ rowptr,
                        int* __restrict__ bsum, int n) {
    __shared__ int sdata[256];
    int t = threadIdx.x, b = blockIdx.x;
    int base = b * 1024 + t * 4;
    int v[4], s = 0;
#pragma unroll
    for (int k = 0; k < 4; ++k) { int i = base + k; v[k] = (i < n) ? cnt[i] : 0; s += v[k]; }
    sdata[t] = s;
    __syncthreads();
    int x = s;
    for (int off = 1; off < 256; off <<= 1) {
        int y = (t >= off) ? sdata[t - off] : 0;
        __syncthreads();
        x += y;
        sdata[t] = x;
        __syncthreads();
    }
    int run = x - s;
    if (t == 255) bsum[b] = x;
#pragma unroll
    for (int k = 0; k < 4; ++k) { int i = base + k; if (i < n) rowptr[i] = run; run += v[k]; }
}

__global__ void k_scan2(int* __restrict__ bsum, int nb) {
    __shared__ int sdata[256];
    int t = threadIdx.x;
    int s = (t < nb) ? bsum[t] : 0;
    sdata[t] = s;
    __syncthreads();
    int x = s;
    for (int off = 1; off < 256; off <<= 1) {
        int y = (t >= off) ? sdata[t - off] : 0;
        __syncthreads();
        x += y;
        sdata[t] = x;
        __syncthreads();
    }
    if (t < nb) bsum[t] = x - s;
}

__global__ void k_scan3(int* __restrict__ rowptr, const int* __restrict__ bsum, int n, int E) {
    int i = blockIdx.x * blockDim.x + threadIdx.x;
    if (i < n) rowptr[i] += bsum[i >> 10];
    else if (i == n) rowptr[n] = E;
}

// ---------------- reorder: NO atomics — pos = rowptr[dst] + rank ----------------

__global__ void k_reorder(const int* __restrict__ src, const int* __restrict__ dst,
                          const float* __restrict__ ew, const float* __restrict__ dinv,
                          const int* __restrict__ rowptr, const int* __restrict__ rank,
                          int2* __restrict__ edges, int nE) {
    int e = blockIdx.x * blockDim.x + threadIdx.x;
    if (e < nE) {
        int s = src[e];
        int d = dst[e];
        float w = dinv[s] * ew[e] * dinv[d];
        int pos = rowptr[d] + rank[e];
        edges[pos] = make_int2(s, __float_as_int(w));
    }
}

// ---------------- aggregate: out[n,:] = dinv[n]^2*h[n,:] + sum_e w_e * hb[src_e,:] ----
// one wave per node, lane = feature. hb row = 64*bf16 = 128 B = exactly one cache
// line, fully consumed by the wave gather (proven layout — round-2's quarter
// slicing regressed: 4 partial lines/wave + 4x edge re-read). 8-deep edge unroll
// for more gather MLP (VGPR headroom: 12 used).

__launch_bounds__(256)
__global__ void k_aggregate(const float* __restrict__ h, const unsigned short* __restrict__ hb,
                            const float* __restrict__ dinv,
                            const int2* __restrict__ edges, const int* __restrict__ rowptr,
                            float* __restrict__ out, int N) {
    int n = (blockIdx.x * 256 + threadIdx.x) >> 6;
    int lane = threadIdx.x & 63;
    if (n >= N) return;

    float dn = dinv[n];
    float acc = dn * dn * h[(size_t)n * HID + lane];

    int beg = rowptr[n], end = rowptr[n + 1];
    int j = beg;
    for (; j + 7 < end; j += 8) {
        int2 p0 = edges[j];
        int2 p1 = edges[j + 1];
        int2 p2 = edges[j + 2];
        int2 p3 = edges[j + 3];
        int2 p4 = edges[j + 4];
        int2 p5 = edges[j + 5];
        int2 p6 = edges[j + 6];
        int2 p7 = edges[j + 7];
        float h0 = bf2f(hb[(size_t)p0.x * HID + lane]);
        float h1 = bf2f(hb[(size_t)p1.x * HID + lane]);
        float h2 = bf2f(hb[(size_t)p2.x * HID + lane]);
        float h3 = bf2f(hb[(size_t)p3.x * HID + lane]);
        float h4 = bf2f(hb[(size_t)p4.x * HID + lane]);
        float h5 = bf2f(hb[(size_t)p5.x * HID + lane]);
        float h6 = bf2f(hb[(size_t)p6.x * HID + lane]);
        float h7 = bf2f(hb[(size_t)p7.x * HID + lane]);
        acc = fmaf(__int_as_float(p0.y), h0, acc);
        acc = fmaf(__int_as_float(p1.y), h1, acc);
        acc = fmaf(__int_as_float(p2.y), h2, acc);
        acc = fmaf(__int_as_float(p3.y), h3, acc);
        acc = fmaf(__int_as_float(p4.y), h4, acc);
        acc = fmaf(__int_as_float(p5.y), h5, acc);
        acc = fmaf(__int_as_float(p6.y), h6, acc);
        acc = fmaf(__int_as_float(p7.y), h7, acc);
    }
    for (; j < end; ++j) {
        int2 p = edges[j];
        acc = fmaf(__int_as_float(p.y), bf2f(hb[(size_t)p.x * HID + lane]), acc);
    }
    out[(size_t)n * HID + lane] = acc;
}

// ---------------- tiled GEMM: out[M,64] = act(A[M,K]) @ W[K,64]; also bf16 copy ----------------

template <int K_, bool RELU_BIAS>
__launch_bounds__(256)
__global__ void k_gemm_n64(const float* __restrict__ A, const float* __restrict__ W,
                           const float* __restrict__ bias, float* __restrict__ out,
                           unsigned short* __restrict__ outb, int M) {
    constexpr int BK = 16;
    __shared__ float As[BK][68];
    __shared__ float Ws[BK][64];

    const int t  = threadIdx.x;
    const int tx = t & 15;
    const int ty = t >> 4;
    const int row0 = blockIdx.x * 64;

    const int lr = t >> 2;
    const int lk = (t & 3) * 4;

    float acc[4][4] = {};

    for (int k0 = 0; k0 < K_; k0 += BK) {
        float4 av = make_float4(0.f, 0.f, 0.f, 0.f);
        int ar = row0 + lr;
        if (ar < M) {
            av = *(const float4*)&A[(long long)ar * K_ + k0 + lk];
            if (RELU_BIAS) {
                const float4 bv = *(const float4*)&bias[k0 + lk];
                av.x = fmaxf(av.x + bv.x, 0.f);
                av.y = fmaxf(av.y + bv.y, 0.f);
                av.z = fmaxf(av.z + bv.z, 0.f);
                av.w = fmaxf(av.w + bv.w, 0.f);
            }
        }
        As[lk + 0][lr] = av.x;
        As[lk + 1][lr] = av.y;
        As[lk + 2][lr] = av.z;
        As[lk + 3][lr] = av.w;

        *(float4*)&Ws[t >> 4][(t & 15) * 4] =
            *(const float4*)&W[(long long)(k0 + (t >> 4)) * 64 + (t & 15) * 4];

        __syncthreads();

#pragma unroll
        for (int kk = 0; kk < BK; ++kk) {
            float4 a4 = *(const float4*)&As[kk][ty * 4];
            float4 b4 = *(const float4*)&Ws[kk][tx * 4];
            float a[4] = {a4.x, a4.y, a4.z, a4.w};
            float b[4] = {b4.x, b4.y, b4.z, b4.w};
#pragma unroll
            for (int i = 0; i < 4; ++i)
#pragma unroll
                for (int j = 0; j < 4; ++j)
                    acc[i][j] = fmaf(a[i], b[j], acc[i][j]);
        }
        __syncthreads();
    }

#pragma unroll
    for (int i = 0; i < 4; ++i) {
        int r = row0 + ty * 4 + i;
        if (r < M) {
            *(float4*)&out[(long long)r * 64 + tx * 4] =
                make_float4(acc[i][0], acc[i][1], acc[i][2], acc[i][3]);
            ushort4 hv;
            hv.x = f2bf(acc[i][0]);
            hv.y = f2bf(acc[i][1]);
            hv.z = f2bf(acc[i][2]);
            hv.w = f2bf(acc[i][3]);
            *(ushort4*)&outb[(long long)r * 64 + tx * 4] = hv;
        }
    }
}

// ---------------- final: out[n,:5] = relu(agg[n,:]+b2) @ Wfc + bfc ----------------

__launch_bounds__(256)
__global__ void k_final(const float* __restrict__ agg, const float* __restrict__ b2,
                        const float* __restrict__ Wfc, const float* __restrict__ bfc,
                        float* __restrict__ out, int N) {
    __shared__ float Wsf[HID * OUT_DIM];
    __shared__ float bs[HID];
    int t = threadIdx.x;
    for (int i = t; i < HID * OUT_DIM; i += 256) Wsf[i] = Wfc[i];
    if (t < HID) bs[t] = b2[t];
    __syncthreads();

    int n = blockIdx.x * blockDim.x + t;
    if (n >= N) return;

    float acc[OUT_DIM];
#pragma unroll
    for (int o = 0; o < OUT_DIM; ++o) acc[o] = bfc[o];

    const float4* ag = (const float4*)&agg[(long long)n * HID];
#pragma unroll
    for (int k4 = 0; k4 < HID / 4; ++k4) {
        float4 v4 = ag[k4];
        float v[4] = {v4.x, v4.y, v4.z, v4.w};
#pragma unroll
        for (int j = 0; j < 4; ++j) {
            int k = k4 * 4 + j;
            float f = fmaxf(v[j] + bs[k], 0.f);
#pragma unroll
            for (int o = 0; o < OUT_DIM; ++o)
                acc[o] = fmaf(f, Wsf[k * OUT_DIM + o], acc[o]);
        }
    }
#pragma unroll
    for (int o = 0; o < OUT_DIM; ++o) out[(long long)n * OUT_DIM + o] = acc[o];
}

// ---------------- host launch ----------------

static inline size_t align_up(size_t x, size_t a) { return (x + a - 1) & ~(a - 1); }

extern "C" void kernel_launch(void* const* d_in, const int* in_sizes, int n_in,
                              void* d_out, int out_size, void* d_ws, size_t ws_size,
                              hipStream_t stream) {
    const float* x   = (const float*)d_in[0];
    const int*   ei  = (const int*)d_in[1];   // [2][E] int32
    const float* ew  = (const float*)d_in[2];
    const float* W1  = (const float*)d_in[3];
    const float* b1  = (const float*)d_in[4];
    const float* W2  = (const float*)d_in[5];
    const float* b2  = (const float*)d_in[6];
    const float* Wfc = (const float*)d_in[7];
    const float* bfc = (const float*)d_in[8];
    float* out = (float*)d_out;

    const int E = in_sizes[2];              // 3200000
    const int N = in_sizes[0] / IN_DIM;     // 100000
    const int* src = ei;
    const int* dst = ei + E;

    // workspace carve (hb aliases rank: rank is dead after k_reorder,
    // GEMM1 writes hb strictly after — same stream, sequential)
    char* p = (char*)d_ws;
    unsigned long long* packed = (unsigned long long*)p; p += align_up((size_t)N * 8, 256);
    float* dinv   = (float*)p;  p += align_up((size_t)N * 4, 256);
    int*   cnt    = (int*)p;    p += align_up((size_t)N * 4, 256);
    int*   rowptr = (int*)p;    p += align_up((size_t)(N + 1) * 4, 256);
    int*   bsum   = (int*)p;    p += align_up((size_t)256 * 4, 256);
    int*   rank   = (int*)p;    p += align_up((size_t)E * 4, 256);   // 12.8 MB
    unsigned short* hb = (unsigned short*)rank;                       // N*HID*2 = 12.8 MB
    int2*  edges  = (int2*)p;   p += align_up((size_t)E * 8, 256);
    float* bufA   = (float*)p;  p += align_up((size_t)N * HID * 4, 256);
    float* bufB   = (float*)p;  p += align_up((size_t)N * HID * 4, 256);
    (void)ws_size; (void)n_in; (void)out_size;

    const int BS = 256;
    dim3 blk(BS);
    int gN  = (N + BS - 1) / BS;
    int gN1 = (N + 1 + BS - 1) / BS;
    int gE  = (E + BS - 1) / BS;
    int gE4 = (E + BS * 4 - 1) / (BS * 4);
    int gM  = (N + 63) / 64;
    int nb  = (N + 1023) / 1024;
    int gAg = (N + 3) / 4;

    // CSR build: 1 scattered atomic per edge total
    k_init<<<gN, blk, 0, stream>>>(packed, N);
    k_hist4<<<gE4, blk, 0, stream>>>(dst, ew, packed, rank, E);
    k_dinv<<<gN, blk, 0, stream>>>(packed, dinv, cnt, N);
    k_scan1<<<nb, blk, 0, stream>>>(cnt, rowptr, bsum, N);
    k_scan2<<<1, blk, 0, stream>>>(bsum, nb);
    k_scan3<<<gN1, blk, 0, stream>>>(rowptr, bsum, N, E);
    k_reorder<<<gE, blk, 0, stream>>>(src, dst, ew, dinv, rowptr, rank, edges, E);

    // layer 1 (hb overwrites rank — rank dead from here on)
    k_gemm_n64<IN_DIM, false><<<gM, blk, 0, stream>>>(x, W1, nullptr, bufA, hb, N);
    k_aggregate<<<gAg, blk, 0, stream>>>(bufA, hb, dinv, edges, rowptr, bufB, N);

    // layer 2
    k_gemm_n64<HID, true><<<gM, blk, 0, stream>>>(bufB, W2, b1, bufA, hb, N);
    k_aggregate<<<gAg, blk, 0, stream>>>(bufA, hb, dinv, edges, rowptr, bufB, N);

    // final FC
    k_final<<<gN, blk, 0, stream>>>(bufB, b2, Wfc, bfc, out, N);
}

// Round 6
// 748.040 us; speedup vs baseline: 1.6189x; 1.0994x over previous
//
#include <hip/hip_runtime.h>

#define IN_DIM 512
#define HID 64
#define OUT_DIM 5

// ---------------- bf16 helpers (RNE) ----------------

__device__ __forceinline__ unsigned short f2bf(float f) {
    unsigned u = __float_as_uint(f);
    u += 0x7FFF + ((u >> 16) & 1);
    return (unsigned short)(u >> 16);
}
__device__ __forceinline__ float bf2f(unsigned short b) {
    return __uint_as_float(((unsigned)b) << 16);
}

// ---------------- init: packed deg/count accumulator = 0 ----------------

__global__ void k_init(unsigned long long* __restrict__ packed, int n) {
    int i = blockIdx.x * blockDim.x + threadIdx.x;
    if (i < n) packed[i] = 0ULL;
}

// ---------------- fused GEMM1 + hist ----------------
// GEMM1 (x @ W1 -> bufA fp32 + hb bf16) has NO dependency on the CSR build;
// hist is fabric-atomic-bound (VALUBusy 0.8%, HBM 11%) so its 148 us leave the
// CUs idle. Block-split fusion overlaps them: blocks [0,gemmBlocks) run GEMM,
// the rest run hist. Disjoint data; no inter-block ordering assumed.
// hist: packed[d] bits[63:44]=count, [43:0]=sum(ew) 12.32 fixed pt; atomic
// return = edge's rank in its dst bucket (4-wide proven throughput-neutral,
// kept for the vectorized int4/float4 edge reads).

__launch_bounds__(256)
__global__ void k_gemm1_hist(const float* __restrict__ A, const float* __restrict__ W,
                             float* __restrict__ out, unsigned short* __restrict__ outb, int M,
                             const int* __restrict__ dst, const float* __restrict__ ew,
                             unsigned long long* __restrict__ packed, int* __restrict__ rank,
                             int nE, int gemmBlocks) {
    if ((int)blockIdx.x < gemmBlocks) {
        constexpr int K_ = IN_DIM;
        constexpr int BK = 16;
        __shared__ float As[BK][68];
        __shared__ float Ws[BK][64];

        const int t  = threadIdx.x;
        const int tx = t & 15;
        const int ty = t >> 4;
        const int row0 = blockIdx.x * 64;

        const int lr = t >> 2;
        const int lk = (t & 3) * 4;

        float acc[4][4] = {};

        for (int k0 = 0; k0 < K_; k0 += BK) {
            float4 av = make_float4(0.f, 0.f, 0.f, 0.f);
            int ar = row0 + lr;
            if (ar < M) av = *(const float4*)&A[(long long)ar * K_ + k0 + lk];
            As[lk + 0][lr] = av.x;
            As[lk + 1][lr] = av.y;
            As[lk + 2][lr] = av.z;
            As[lk + 3][lr] = av.w;

            *(float4*)&Ws[t >> 4][(t & 15) * 4] =
                *(const float4*)&W[(long long)(k0 + (t >> 4)) * 64 + (t & 15) * 4];

            __syncthreads();

#pragma unroll
            for (int kk = 0; kk < BK; ++kk) {
                float4 a4 = *(const float4*)&As[kk][ty * 4];
                float4 b4 = *(const float4*)&Ws[kk][tx * 4];
                float a[4] = {a4.x, a4.y, a4.z, a4.w};
                float b[4] = {b4.x, b4.y, b4.z, b4.w};
#pragma unroll
                for (int i = 0; i < 4; ++i)
#pragma unroll
                    for (int j = 0; j < 4; ++j)
                        acc[i][j] = fmaf(a[i], b[j], acc[i][j]);
            }
            __syncthreads();
        }

#pragma unroll
        for (int i = 0; i < 4; ++i) {
            int r = row0 + ty * 4 + i;
            if (r < M) {
                *(float4*)&out[(long long)r * 64 + tx * 4] =
                    make_float4(acc[i][0], acc[i][1], acc[i][2], acc[i][3]);
                ushort4 hv;
                hv.x = f2bf(acc[i][0]);
                hv.y = f2bf(acc[i][1]);
                hv.z = f2bf(acc[i][2]);
                hv.w = f2bf(acc[i][3]);
                *(ushort4*)&outb[(long long)r * 64 + tx * 4] = hv;
            }
        }
    } else {
        int base = ((blockIdx.x - gemmBlocks) * 256 + threadIdx.x) * 4;
        if (base + 3 < nE) {
            int4   d4 = *(const int4*)&dst[base];
            float4 w4 = *(const float4*)&ew[base];
            unsigned long long f0 = (unsigned long long)(w4.x * 4294967296.0);
            unsigned long long f1 = (unsigned long long)(w4.y * 4294967296.0);
            unsigned long long f2 = (unsigned long long)(w4.z * 4294967296.0);
            unsigned long long f3 = (unsigned long long)(w4.w * 4294967296.0);
            unsigned long long o0 = atomicAdd(&packed[d4.x], (1ULL << 44) | f0);
            unsigned long long o1 = atomicAdd(&packed[d4.y], (1ULL << 44) | f1);
            unsigned long long o2 = atomicAdd(&packed[d4.z], (1ULL << 44) | f2);
            unsigned long long o3 = atomicAdd(&packed[d4.w], (1ULL << 44) | f3);
            int4 r4;
            r4.x = (int)(o0 >> 44);
            r4.y = (int)(o1 >> 44);
            r4.z = (int)(o2 >> 44);
            r4.w = (int)(o3 >> 44);
            *(int4*)&rank[base] = r4;
        } else {
            for (int e = base; e < nE; ++e) {
                int d = dst[e];
                unsigned long long fx = (unsigned long long)(ew[e] * 4294967296.0);
                unsigned long long old = atomicAdd(&packed[d], (1ULL << 44) | fx);
                rank[e] = (int)(old >> 44);
            }
        }
    }
}

// ---------------- scan1 + dinv fused: reads packed directly ----------------
// dinv = rsqrt(1 + sum_ew); cnt extracted inline for the block-level scan.

__global__ void k_scan1d(const unsigned long long* __restrict__ packed,
                         float* __restrict__ dinv, int* __restrict__ rowptr,
                         int* __restrict__ bsum, int n) {
    __shared__ int sdata[256];
    int t = threadIdx.x, b = blockIdx.x;
    int base = b * 1024 + t * 4;
    int v[4], s = 0;
#pragma unroll
    for (int k = 0; k < 4; ++k) {
        int i = base + k;
        int c = 0;
        if (i < n) {
            unsigned long long p = packed[i];
            c = (int)(p >> 44);
            double ewsum = (double)(p & ((1ULL << 44) - 1)) * (1.0 / 4294967296.0);
            dinv[i] = rsqrtf(1.0f + (float)ewsum);
        }
        v[k] = c;
        s += c;
    }
    sdata[t] = s;
    __syncthreads();
    int x = s;
    for (int off = 1; off < 256; off <<= 1) {
        int y = (t >= off) ? sdata[t - off] : 0;
        __syncthreads();
        x += y;
        sdata[t] = x;
        __syncthreads();
    }
    int run = x - s;
    if (t == 255) bsum[b] = x;
#pragma unroll
    for (int k = 0; k < 4; ++k) { int i = base + k; if (i < n) rowptr[i] = run; run += v[k]; }
}

__global__ void k_scan2(int* __restrict__ bsum, int nb) {
    __shared__ int sdata[256];
    int t = threadIdx.x;
    int s = (t < nb) ? bsum[t] : 0;
    sdata[t] = s;
    __syncthreads();
    int x = s;
    for (int off = 1; off < 256; off <<= 1) {
        int y = (t >= off) ? sdata[t - off] : 0;
        __syncthreads();
        x += y;
        sdata[t] = x;
        __syncthreads();
    }
    if (t < nb) bsum[t] = x - s;
}

__global__ void k_scan3(int* __restrict__ rowptr, const int* __restrict__ bsum, int n, int E) {
    int i = blockIdx.x * blockDim.x + threadIdx.x;
    if (i < n) rowptr[i] += bsum[i >> 10];
    else if (i == n) rowptr[n] = E;
}

// ---------------- reorder: NO atomics — pos = rowptr[dst] + rank ----------------

__global__ void k_reorder(const int* __restrict__ src, const int* __restrict__ dst,
                          const float* __restrict__ ew, const float* __restrict__ dinv,
                          const int* __restrict__ rowptr, const int* __restrict__ rank,
                          int2* __restrict__ edges, int nE) {
    int e = blockIdx.x * blockDim.x + threadIdx.x;
    if (e < nE) {
        int s = src[e];
        int d = dst[e];
        float w = dinv[s] * ew[e] * dinv[d];
        int pos = rowptr[d] + rank[e];
        edges[pos] = make_int2(s, __float_as_int(w));
    }
}

// ---------------- aggregate: out[n,:] = dinv[n]^2*h[n,:] + sum_e w_e * hb[src_e,:] ----
// one wave per node, lane = feature. hb row = 64*bf16 = 128 B = exactly one cache
// line, fully consumed by the wave gather. 8-deep edge unroll for gather MLP.

__launch_bounds__(256)
__global__ void k_aggregate(const float* __restrict__ h, const unsigned short* __restrict__ hb,
                            const float* __restrict__ dinv,
                            const int2* __restrict__ edges, const int* __restrict__ rowptr,
                            float* __restrict__ out, int N) {
    int n = (blockIdx.x * 256 + threadIdx.x) >> 6;
    int lane = threadIdx.x & 63;
    if (n >= N) return;

    float dn = dinv[n];
    float acc = dn * dn * h[(size_t)n * HID + lane];

    int beg = rowptr[n], end = rowptr[n + 1];
    int j = beg;
    for (; j + 7 < end; j += 8) {
        int2 p0 = edges[j];
        int2 p1 = edges[j + 1];
        int2 p2 = edges[j + 2];
        int2 p3 = edges[j + 3];
        int2 p4 = edges[j + 4];
        int2 p5 = edges[j + 5];
        int2 p6 = edges[j + 6];
        int2 p7 = edges[j + 7];
        float h0 = bf2f(hb[(size_t)p0.x * HID + lane]);
        float h1 = bf2f(hb[(size_t)p1.x * HID + lane]);
        float h2 = bf2f(hb[(size_t)p2.x * HID + lane]);
        float h3 = bf2f(hb[(size_t)p3.x * HID + lane]);
        float h4 = bf2f(hb[(size_t)p4.x * HID + lane]);
        float h5 = bf2f(hb[(size_t)p5.x * HID + lane]);
        float h6 = bf2f(hb[(size_t)p6.x * HID + lane]);
        float h7 = bf2f(hb[(size_t)p7.x * HID + lane]);
        acc = fmaf(__int_as_float(p0.y), h0, acc);
        acc = fmaf(__int_as_float(p1.y), h1, acc);
        acc = fmaf(__int_as_float(p2.y), h2, acc);
        acc = fmaf(__int_as_float(p3.y), h3, acc);
        acc = fmaf(__int_as_float(p4.y), h4, acc);
        acc = fmaf(__int_as_float(p5.y), h5, acc);
        acc = fmaf(__int_as_float(p6.y), h6, acc);
        acc = fmaf(__int_as_float(p7.y), h7, acc);
    }
    for (; j < end; ++j) {
        int2 p = edges[j];
        acc = fmaf(__int_as_float(p.y), bf2f(hb[(size_t)p.x * HID + lane]), acc);
    }
    out[(size_t)n * HID + lane] = acc;
}

// ---------------- tiled GEMM: out[M,64] = act(A[M,K]) @ W[K,64]; also bf16 copy ----------------

template <int K_, bool RELU_BIAS>
__launch_bounds__(256)
__global__ void k_gemm_n64(const float* __restrict__ A, const float* __restrict__ W,
                           const float* __restrict__ bias, float* __restrict__ out,
                           unsigned short* __restrict__ outb, int M) {
    constexpr int BK = 16;
    __shared__ float As[BK][68];
    __shared__ float Ws[BK][64];

    const int t  = threadIdx.x;
    const int tx = t & 15;
    const int ty = t >> 4;
    const int row0 = blockIdx.x * 64;

    const int lr = t >> 2;
    const int lk = (t & 3) * 4;

    float acc[4][4] = {};

    for (int k0 = 0; k0 < K_; k0 += BK) {
        float4 av = make_float4(0.f, 0.f, 0.f, 0.f);
        int ar = row0 + lr;
        if (ar < M) {
            av = *(const float4*)&A[(long long)ar * K_ + k0 + lk];
            if (RELU_BIAS) {
                const float4 bv = *(const float4*)&bias[k0 + lk];
                av.x = fmaxf(av.x + bv.x, 0.f);
                av.y = fmaxf(av.y + bv.y, 0.f);
                av.z = fmaxf(av.z + bv.z, 0.f);
                av.w = fmaxf(av.w + bv.w, 0.f);
            }
        }
        As[lk + 0][lr] = av.x;
        As[lk + 1][lr] = av.y;
        As[lk + 2][lr] = av.z;
        As[lk + 3][lr] = av.w;

        *(float4*)&Ws[t >> 4][(t & 15) * 4] =
            *(const float4*)&W[(long long)(k0 + (t >> 4)) * 64 + (t & 15) * 4];

        __syncthreads();

#pragma unroll
        for (int kk = 0; kk < BK; ++kk) {
            float4 a4 = *(const float4*)&As[kk][ty * 4];
            float4 b4 = *(const float4*)&Ws[kk][tx * 4];
            float a[4] = {a4.x, a4.y, a4.z, a4.w};
            float b[4] = {b4.x, b4.y, b4.z, b4.w};
#pragma unroll
            for (int i = 0; i < 4; ++i)
#pragma unroll
                for (int j = 0; j < 4; ++j)
                    acc[i][j] = fmaf(a[i], b[j], acc[i][j]);
        }
        __syncthreads();
    }

#pragma unroll
    for (int i = 0; i < 4; ++i) {
        int r = row0 + ty * 4 + i;
        if (r < M) {
            *(float4*)&out[(long long)r * 64 + tx * 4] =
                make_float4(acc[i][0], acc[i][1], acc[i][2], acc[i][3]);
            ushort4 hv;
            hv.x = f2bf(acc[i][0]);
            hv.y = f2bf(acc[i][1]);
            hv.z = f2bf(acc[i][2]);
            hv.w = f2bf(acc[i][3]);
            *(ushort4*)&outb[(long long)r * 64 + tx * 4] = hv;
        }
    }
}

// ---------------- final: out[n,:5] = relu(agg[n,:]+b2) @ Wfc + bfc ----------------

__launch_bounds__(256)
__global__ void k_final(const float* __restrict__ agg, const float* __restrict__ b2,
                        const float* __restrict__ Wfc, const float* __restrict__ bfc,
                        float* __restrict__ out, int N) {
    __shared__ float Wsf[HID * OUT_DIM];
    __shared__ float bs[HID];
    int t = threadIdx.x;
    for (int i = t; i < HID * OUT_DIM; i += 256) Wsf[i] = Wfc[i];
    if (t < HID) bs[t] = b2[t];
    __syncthreads();

    int n = blockIdx.x * blockDim.x + t;
    if (n >= N) return;

    float acc[OUT_DIM];
#pragma unroll
    for (int o = 0; o < OUT_DIM; ++o) acc[o] = bfc[o];

    const float4* ag = (const float4*)&agg[(long long)n * HID];
#pragma unroll
    for (int k4 = 0; k4 < HID / 4; ++k4) {
        float4 v4 = ag[k4];
        float v[4] = {v4.x, v4.y, v4.z, v4.w};
#pragma unroll
        for (int j = 0; j < 4; ++j) {
            int k = k4 * 4 + j;
            float f = fmaxf(v[j] + bs[k], 0.f);
#pragma unroll
            for (int o = 0; o < OUT_DIM; ++o)
                acc[o] = fmaf(f, Wsf[k * OUT_DIM + o], acc[o]);
        }
    }
#pragma unroll
    for (int o = 0; o < OUT_DIM; ++o) out[(long long)n * OUT_DIM + o] = acc[o];
}

// ---------------- host launch ----------------

static inline size_t align_up(size_t x, size_t a) { return (x + a - 1) & ~(a - 1); }

extern "C" void kernel_launch(void* const* d_in, const int* in_sizes, int n_in,
                              void* d_out, int out_size, void* d_ws, size_t ws_size,
                              hipStream_t stream) {
    const float* x   = (const float*)d_in[0];
    const int*   ei  = (const int*)d_in[1];   // [2][E] int32
    const float* ew  = (const float*)d_in[2];
    const float* W1  = (const float*)d_in[3];
    const float* b1  = (const float*)d_in[4];
    const float* W2  = (const float*)d_in[5];
    const float* b2  = (const float*)d_in[6];
    const float* Wfc = (const float*)d_in[7];
    const float* bfc = (const float*)d_in[8];
    float* out = (float*)d_out;

    const int E = in_sizes[2];              // 3200000
    const int N = in_sizes[0] / IN_DIM;     // 100000
    const int* src = ei;
    const int* dst = ei + E;

    // workspace carve. Aliasing: rank lives in bufB — rank is read last by
    // k_reorder; bufB is first written by k_aggregate (strictly later, same
    // stream). hb is now a REAL buffer (GEMM1 writes it concurrently with
    // hist writing rank, so the old hb<->rank alias is illegal).
    char* p = (char*)d_ws;
    unsigned long long* packed = (unsigned long long*)p; p += align_up((size_t)N * 8, 256);
    float* dinv   = (float*)p;  p += align_up((size_t)N * 4, 256);
    int*   rowptr = (int*)p;    p += align_up((size_t)(N + 1) * 4, 256);
    int*   bsum   = (int*)p;    p += align_up((size_t)256 * 4, 256);
    unsigned short* hb = (unsigned short*)p; p += align_up((size_t)N * HID * 2, 256); // 12.8 MB
    int2*  edges  = (int2*)p;   p += align_up((size_t)E * 8, 256);   // 25.6 MB
    float* bufA   = (float*)p;  p += align_up((size_t)N * HID * 4, 256);
    float* bufB   = (float*)p;  p += align_up((size_t)N * HID * 4, 256);
    int*   rank   = (int*)bufB;  // E*4 = 12.8 MB <= bufB's 25.6 MB
    (void)ws_size; (void)n_in; (void)out_size;

    const int BS = 256;
    dim3 blk(BS);
    int gN  = (N + BS - 1) / BS;
    int gN1 = (N + 1 + BS - 1) / BS;
    int gE  = (E + BS - 1) / BS;
    int gE4 = (E + BS * 4 - 1) / (BS * 4);
    int gM  = (N + 63) / 64;
    int nb  = (N + 1023) / 1024;
    int gAg = (N + 3) / 4;

    // CSR build overlapped with GEMM1 (independent inputs)
    k_init<<<gN, blk, 0, stream>>>(packed, N);
    k_gemm1_hist<<<gM + gE4, blk, 0, stream>>>(x, W1, bufA, hb, N,
                                               dst, ew, packed, rank, E, gM);
    k_scan1d<<<nb, blk, 0, stream>>>(packed, dinv, rowptr, bsum, N);
    k_scan2<<<1, blk, 0, stream>>>(bsum, nb);
    k_scan3<<<gN1, blk, 0, stream>>>(rowptr, bsum, N, E);
    k_reorder<<<gE, blk, 0, stream>>>(src, dst, ew, dinv, rowptr, rank, edges, E);

    // layer 1 aggregate (writes bufB — rank dead from here on)
    k_aggregate<<<gAg, blk, 0, stream>>>(bufA, hb, dinv, edges, rowptr, bufB, N);

    // layer 2
    k_gemm_n64<HID, true><<<gM, blk, 0, stream>>>(bufB, W2, b1, bufA, hb, N);
    k_aggregate<<<gAg, blk, 0, stream>>>(bufA, hb, dinv, edges, rowptr, bufB, N);

    // final FC
    k_final<<<gN, blk, 0, stream>>>(bufB, b2, Wfc, bfc, out, N);
}